// Round 18
// baseline (583.705 us; speedup 1.0000x reference)
//
#include <hip/hip_runtime.h>
#include <hip/hip_bf16.h>

#define TT 8
#define NN 50000
#define FF 128
#define HH 64
#define CC 4
#define EE 800000
#define NB2 391           // buckets of 128 nodes (ceil(50000/128))
#define CAP 2560          // padded records per (t,bucket): mean 2048, sd ~45 -> 11 sigma
#define BPT 125           // multisplit blocks per timestep (125*6400 = 800000)
#define XWB 196           // xw blocks per timestep (196*256 >= 50000 rows)

typedef unsigned short u16;
typedef unsigned int u32;
typedef __attribute__((ext_vector_type(8))) short bf16x8;
typedef __attribute__((ext_vector_type(4))) float f32x4;
typedef __attribute__((ext_vector_type(4))) int i32x4;

static __device__ __forceinline__ float bflo(u32 w) {
    union { unsigned int i; float f; } v; v.i = w << 16; return v.f;
}
static __device__ __forceinline__ float bfhi(u32 w) {
    union { unsigned int i; float f; } v; v.i = w & 0xFFFF0000u; return v.f;
}
static __device__ __forceinline__ u16 cvt_bf16(float f) {
    __hip_bfloat16 b = __float2bfloat16(f);          // native RNE
    return *reinterpret_cast<u16*>(&b);
}

// ---------------- zero cnt + gcur ----------------
__global__ __launch_bounds__(256) void zero_kernel(int* __restrict__ cnt, int* __restrict__ gcur) {
    int i = blockIdx.x * 256 + threadIdx.x;
    if (i < TT * NN) cnt[i] = 0;
    else if (i < TT * NN + TT * NB2) gcur[i - TT * NN] = 0;
}

// ---------------- multisplit + fused global degree histogram ----------------
// int4 edge loads; LDS 64B line buffers -> full-line flushes only. The global cnt
// histogram rides along (fire-and-forget atomics): deletes csr's LDS-hist pass and
// makes degrees available before xw (dinv computed on the fly downstream).
__global__ __launch_bounds__(256) void multisplit_kernel(const int* __restrict__ edges,
                                                         int* __restrict__ gcur, u32* __restrict__ binned,
                                                         int* __restrict__ cnt) {
    __shared__ u32 sbuf[NB2][16];
    __shared__ int scnt[NB2];
    int bid = blockIdx.x;
    int t = bid & 7;
    int blk = bid >> 3;                       // 0..BPT-1
    const int per = EE / BPT;                 // 6400
    int e0 = blk * per;
    int e1 = e0 + per;

    for (int i = threadIdx.x; i < NB2; i += 256) scnt[i] = 0;
    __syncthreads();

    const int* es = edges + (size_t)(t * 2 + 0) * EE;
    const int* ed = edges + (size_t)(t * 2 + 1) * EE;
    int* gc = gcur + t * NB2;
    int* cw = cnt + t * NN;
    u32* bb = binned + (size_t)t * NB2 * CAP;

    for (int base = e0; base < e1; base += 1024) {
        u32 rec[4]; int pb[4];
        int e = base + threadIdx.x * 4;
        int nv = 0;
        if (e + 3 < e1) nv = 4;
        else if (e < e1) nv = e1 - e;
        if (nv == 4) {
            i32x4 s4 = *reinterpret_cast<const i32x4*>(&es[e]);
            i32x4 d4 = *reinterpret_cast<const i32x4*>(&ed[e]);
            #pragma unroll
            for (int q = 0; q < 4; ++q) {
                int b = d4[q] >> 7;
                u32 r = (u32)s4[q] | ((u32)(d4[q] & 127) << 16);
                atomicAdd(&cw[d4[q]], 1);                    // degree hist (no return)
                int p = atomicAdd(&scnt[b], 1);
                if (p < 16) { sbuf[b][p] = r; pb[q] = -1; }
                else { rec[q] = r; pb[q] = b; }
            }
        } else {
            #pragma unroll
            for (int q = 0; q < 4; ++q) {
                pb[q] = -1;
                if (q < nv) {
                    int src = es[e + q], dst = ed[e + q];
                    int b = dst >> 7;
                    u32 r = (u32)src | ((u32)(dst & 127) << 16);
                    atomicAdd(&cw[dst], 1);
                    int p = atomicAdd(&scnt[b], 1);
                    if (p < 16) sbuf[b][p] = r;
                    else { rec[q] = r; pb[q] = b; }
                }
            }
        }
        __syncthreads();
        // flush any full 64B line
        for (int fb = threadIdx.x; fb < NB2; fb += 256) {
            if (scnt[fb] >= 16) {
                int g = atomicAdd(&gc[fb], 16);
                uint4* dp = (uint4*)(bb + (size_t)fb * CAP + g);
                uint4* sp = (uint4*)&sbuf[fb][0];
                dp[0] = sp[0]; dp[1] = sp[1]; dp[2] = sp[2]; dp[3] = sp[3];
                scnt[fb] = 0;                            // pendings re-append below
            }
        }
        __syncthreads();
        #pragma unroll
        for (int q = 0; q < 4; ++q) {
            if (pb[q] >= 0) {                            // pending retry (count was >16)
                int p = atomicAdd(&scnt[pb[q]], 1);
                if (p < 16) sbuf[pb[q]][p] = rec[q];
                else { int g = atomicAdd(&gc[pb[q]], 1); bb[(size_t)pb[q] * CAP + g] = rec[q]; }  // rare
            }
        }
        __syncthreads();
    }
    // residual (<16 per bucket) partial flush
    for (int fb = threadIdx.x; fb < NB2; fb += 256) {
        int c = scnt[fb];
        if (c > 0) {
            int g = atomicAdd(&gc[fb], c);
            for (int k = 0; k < c; ++k) bb[(size_t)fb * CAP + g + k] = sbuf[fb][k];
        }
    }
}

// ---------------- W transpose + bf16 convert (once per t) ----------------
__global__ __launch_bounds__(256) void wt_prep_kernel(const float* __restrict__ Wg, u16* __restrict__ wt) {
    int t = blockIdx.x;
    const float* w = Wg + t * FF * HH;
    u16* o = wt + (size_t)t * HH * FF;
    for (int i = threadIdx.x; i < FF * HH; i += 256) {
        int k = i >> 6, c = i & 63;
        o[c * FF + k] = cvt_bf16(w[i]);
    }
}

// ---------------- FUSED: csr_scatter || xw (independent after multisplit+hist) ----------------
// 512 threads. Interleaved block mapping co-schedules LDS/atomic-bound csr blocks with
// HBM/MFMA-bound xw blocks on the same CUs. LDS overlaid (csr 10.8KB | xw ylds 36.9KB).
__global__ __launch_bounds__(512) void build_kernel(const u32* __restrict__ binned, const int* __restrict__ gcur,
                                                    const int* __restrict__ cnt,
                                                    u16* __restrict__ srclist, u32* __restrict__ nodeinfo,
                                                    const float* __restrict__ x, const u16* __restrict__ wt,
                                                    u16* __restrict__ y) {
    __shared__ __align__(16) char smem[256 * 72 * 2];   // 36.9KB arena
    int bid = blockIdx.x;
    int tid = threadIdx.x;
    // mapping: first 3136 blocks alternate [xw, csr]; tail 1560 are csr
    int isXw, id;
    if (bid < 2 * XWB * TT) { isXw = ((bid & 1) == 0); id = bid >> 1; }
    else { isXw = 0; id = XWB * TT + (bid - 2 * XWB * TT); }

    if (!isXw) {
        // ---------- csr scatter path ----------
        u32* recs = (u32*)smem;                  // CAP*4 = 10240B
        int* cur = (int*)(smem + CAP * 4);       // 512B
        int t = id / NB2, b = id % NB2;
        int node0 = b * 128;
        int tot = gcur[t * NB2 + b];
        const u32* win = binned + ((size_t)t * NB2 + b) * CAP;
        const int* cw = cnt + t * NN;
        for (int i = tid; i < tot; i += 512) recs[i] = win[i];
        __syncthreads();
        // wave 0: load 128 degree counts, exclusive wave-scan, emit nodeinfo + cursors
        if (tid < 64) {
            int n0 = node0 + 2 * tid;
            int v0 = (n0 < NN) ? cw[n0] : 0;
            int v1 = (n0 + 1 < NN) ? cw[n0 + 1] : 0;
            int pair = v0 + v1;
            int inc = pair;
            #pragma unroll
            for (int off = 1; off < 64; off <<= 1) {
                int u = __shfl_up(inc, off, 64);
                if (tid >= off) inc += u;
            }
            int exclp = inc - pair;
            cur[2 * tid] = exclp;
            cur[2 * tid + 1] = exclp + v0;
            if (n0 < NN)
                nodeinfo[t * NN + n0] = (u32)(b * CAP + exclp) | ((u32)v0 << 20);
            if (n0 + 1 < NN)
                nodeinfo[t * NN + n0 + 1] = (u32)(b * CAP + exclp + v0) | ((u32)v1 << 20);
        }
        __syncthreads();
        u16* sl = srclist + (size_t)t * NB2 * CAP;
        for (int i = tid; i < tot; i += 512) {
            u32 rec = recs[i];
            int d = rec >> 16;
            int p = atomicAdd(&cur[d], 1);
            sl[(size_t)b * CAP + p] = (u16)(rec & 0xFFFF);
        }
    } else {
        // ---------- xw path: y = (x @ Wg) * rsqrt(1+deg), MFMA + LDS-transposed epilogue ----------
        u16 (*ylds)[72] = (u16(*)[72])smem;
        int t = id / XWB, xb = id % XWB;
        int row0 = xb * 256;
        int w = tid >> 6, lane = tid & 63;
        int l15 = lane & 15, lg = lane >> 4;
        const float* xt = x + (size_t)t * NN * FF;
        const u16* wtt = wt + (size_t)t * HH * FF;
        const int* cw = cnt + t * NN;

        f32x4 d[2][4] = {{{0,0,0,0},{0,0,0,0},{0,0,0,0},{0,0,0,0}},
                         {{0,0,0,0},{0,0,0,0},{0,0,0,0},{0,0,0,0}}};
        #pragma unroll
        for (int k0 = 0; k0 < 128; k0 += 32) {
            int kb = k0 + lg * 8;
            union { bf16x8 v; __hip_bfloat162 h[4]; } au[2];
            #pragma unroll
            for (int s = 0; s < 2; ++s) {
                int arow = row0 + w * 32 + s * 16 + l15;
                if (arow < NN) {
                    f32x4 f0 = __builtin_nontemporal_load(reinterpret_cast<const f32x4*>(&xt[(size_t)arow * FF + kb]));
                    f32x4 f1 = __builtin_nontemporal_load(reinterpret_cast<const f32x4*>(&xt[(size_t)arow * FF + kb + 4]));
                    au[s].h[0] = __float22bfloat162_rn(make_float2(f0[0], f0[1]));
                    au[s].h[1] = __float22bfloat162_rn(make_float2(f0[2], f0[3]));
                    au[s].h[2] = __float22bfloat162_rn(make_float2(f1[0], f1[1]));
                    au[s].h[3] = __float22bfloat162_rn(make_float2(f1[2], f1[3]));
                } else {
                    au[s].v = (bf16x8){0,0,0,0,0,0,0,0};
                }
            }
            #pragma unroll
            for (int n = 0; n < 4; ++n) {
                bf16x8 bf = *reinterpret_cast<const bf16x8*>(&wtt[(size_t)(n * 16 + l15) * FF + kb]);
                d[0][n] = __builtin_amdgcn_mfma_f32_16x16x32_bf16(au[0].v, bf, d[0][n], 0, 0, 0);
                d[1][n] = __builtin_amdgcn_mfma_f32_16x16x32_bf16(au[1].v, bf, d[1][n], 0, 0, 0);
            }
        }
        #pragma unroll
        for (int s = 0; s < 2; ++s) {
            int rl = w * 32 + s * 16 + lg * 4;
            float dv[4];
            #pragma unroll
            for (int i = 0; i < 4; ++i) {
                int grow = row0 + rl + i;
                dv[i] = (grow < NN) ? rsqrtf(1.f + (float)cw[grow]) : 0.f;
            }
            #pragma unroll
            for (int n = 0; n < 4; ++n) {
                int col = n * 16 + l15;
                #pragma unroll
                for (int i = 0; i < 4; ++i)
                    ylds[rl + i][col] = cvt_bf16(d[s][n][i] * dv[i]);
            }
        }
        __syncthreads();
        u16* yt = y + (size_t)t * NN * HH;
        #pragma unroll
        for (int it = 0; it < 4; ++it) {
            int idx = it * 512 + tid;
            int r = idx >> 3, c8 = (idx & 7) * 8;
            int grow = row0 + r;
            if (grow < NN)
                *reinterpret_cast<uint4*>(&yt[(size_t)grow * HH + c8]) =
                    *reinterpret_cast<const uint4*>(&ylds[r][c8]);
        }
    }
}

// ---------------- gather-aggregate over all T (single pass, full 128B rows) ----------------
// r8 structure + 32-edge interleaved main level (8 gathers in flight/lane; r9 showed the
// random path sustains 2.78TB/s with deeper MLP; r10's regression was consecutive ordering,
// this keeps r8's interleaved order). dinv recomputed from nodeinfo's packed degree.
__global__ __launch_bounds__(256) void agg_kernel(const u16* __restrict__ y,
                                                  const u32* __restrict__ nodeinfo, const u16* __restrict__ srclist,
                                                  const float* __restrict__ bg, float* __restrict__ acc) {
    int node = blockIdx.x * 4 + (threadIdx.x >> 6);
    int lane = threadIdx.x & 63;
    int sub = lane >> 4;            // edge slot 0..3
    int fo = lane & 15;             // feature quad: feats fo*4 .. fo*4+3
    float a0 = 0.f, a1 = 0.f, a2 = 0.f, a3 = 0.f;
    for (int t = 0; t < TT; ++t) {
        const u16* yt = y + (size_t)t * NN * HH;
        u32 info = nodeinfo[t * NN + node];
        int cnt = info >> 20;
        const u16* sl = srclist + (size_t)t * NB2 * CAP + (info & 0xFFFFF);
        float s0 = 0.f, s1 = 0.f, s2 = 0.f, s3 = 0.f;
        int j = 0;
        for (; j + 32 <= cnt; j += 32) {
            int e0 = sl[j + sub],      e1 = sl[j + 4 + sub],  e2 = sl[j + 8 + sub],  e3 = sl[j + 12 + sub];
            int e4 = sl[j + 16 + sub], e5 = sl[j + 20 + sub], e6 = sl[j + 24 + sub], e7 = sl[j + 28 + sub];
            uint2 v0 = *reinterpret_cast<const uint2*>(&yt[(size_t)e0 * HH + fo * 4]);
            uint2 v1 = *reinterpret_cast<const uint2*>(&yt[(size_t)e1 * HH + fo * 4]);
            uint2 v2 = *reinterpret_cast<const uint2*>(&yt[(size_t)e2 * HH + fo * 4]);
            uint2 v3 = *reinterpret_cast<const uint2*>(&yt[(size_t)e3 * HH + fo * 4]);
            uint2 v4 = *reinterpret_cast<const uint2*>(&yt[(size_t)e4 * HH + fo * 4]);
            uint2 v5 = *reinterpret_cast<const uint2*>(&yt[(size_t)e5 * HH + fo * 4]);
            uint2 v6 = *reinterpret_cast<const uint2*>(&yt[(size_t)e6 * HH + fo * 4]);
            uint2 v7 = *reinterpret_cast<const uint2*>(&yt[(size_t)e7 * HH + fo * 4]);
            s0 += ((bflo(v0.x) + bflo(v1.x)) + (bflo(v2.x) + bflo(v3.x)))
                + ((bflo(v4.x) + bflo(v5.x)) + (bflo(v6.x) + bflo(v7.x)));
            s1 += ((bfhi(v0.x) + bfhi(v1.x)) + (bfhi(v2.x) + bfhi(v3.x)))
                + ((bfhi(v4.x) + bfhi(v5.x)) + (bfhi(v6.x) + bfhi(v7.x)));
            s2 += ((bflo(v0.y) + bflo(v1.y)) + (bflo(v2.y) + bflo(v3.y)))
                + ((bflo(v4.y) + bflo(v5.y)) + (bflo(v6.y) + bflo(v7.y)));
            s3 += ((bfhi(v0.y) + bfhi(v1.y)) + (bfhi(v2.y) + bfhi(v3.y)))
                + ((bfhi(v4.y) + bfhi(v5.y)) + (bfhi(v6.y) + bfhi(v7.y)));
        }
        if (j + 16 <= cnt) {
            int e0 = sl[j + sub], e1 = sl[j + 4 + sub], e2 = sl[j + 8 + sub], e3 = sl[j + 12 + sub];
            uint2 v0 = *reinterpret_cast<const uint2*>(&yt[(size_t)e0 * HH + fo * 4]);
            uint2 v1 = *reinterpret_cast<const uint2*>(&yt[(size_t)e1 * HH + fo * 4]);
            uint2 v2 = *reinterpret_cast<const uint2*>(&yt[(size_t)e2 * HH + fo * 4]);
            uint2 v3 = *reinterpret_cast<const uint2*>(&yt[(size_t)e3 * HH + fo * 4]);
            s0 += (bflo(v0.x) + bflo(v1.x)) + (bflo(v2.x) + bflo(v3.x));
            s1 += (bfhi(v0.x) + bfhi(v1.x)) + (bfhi(v2.x) + bfhi(v3.x));
            s2 += (bflo(v0.y) + bflo(v1.y)) + (bflo(v2.y) + bflo(v3.y));
            s3 += (bfhi(v0.y) + bfhi(v1.y)) + (bfhi(v2.y) + bfhi(v3.y));
            j += 16;
        }
        for (; j < cnt; j += 4) {
            int e = j + sub;
            uint2 v = make_uint2(0u, 0u);
            if (e < cnt) {
                int srcid = sl[e];
                v = *reinterpret_cast<const uint2*>(&yt[(size_t)srcid * HH + fo * 4]);
            }
            s0 += bflo(v.x);
            s1 += bfhi(v.x);
            s2 += bflo(v.y);
            s3 += bfhi(v.y);
        }
        s0 += __shfl_xor(s0, 16, 64); s0 += __shfl_xor(s0, 32, 64);
        s1 += __shfl_xor(s1, 16, 64); s1 += __shfl_xor(s1, 32, 64);
        s2 += __shfl_xor(s2, 16, 64); s2 += __shfl_xor(s2, 32, 64);
        s3 += __shfl_xor(s3, 16, 64); s3 += __shfl_xor(s3, 32, 64);
        // self loop (y already scaled by src dinv)
        uint2 sv = *reinterpret_cast<const uint2*>(&yt[(size_t)node * HH + fo * 4]);
        s0 += bflo(sv.x);
        s1 += bfhi(sv.x);
        s2 += bflo(sv.y);
        s3 += bfhi(sv.y);
        float dvv = rsqrtf(1.f + (float)cnt);
        float4 bgv = *reinterpret_cast<const float4*>(&bg[t * HH + fo * 4]);
        a0 += fmaxf(dvv * s0 + bgv.x, 0.f);
        a1 += fmaxf(dvv * s1 + bgv.y, 0.f);
        a2 += fmaxf(dvv * s2 + bgv.z, 0.f);
        a3 += fmaxf(dvv * s3 + bgv.w, 0.f);
    }
    if (sub == 0) {
        float4 o = make_float4(a0, a1, a2, a3);
        *reinterpret_cast<float4*>(&acc[(size_t)node * HH + fo * 4]) = o;
    }
}

// ---------------- per-node MLP head + log_softmax ----------------
__global__ __launch_bounds__(256) void head_kernel(const float* __restrict__ acc,
                                                   const float* __restrict__ W1, const float* __restrict__ b1,
                                                   const float* __restrict__ W2, const float* __restrict__ b2,
                                                   const float* __restrict__ W3, const float* __restrict__ b3,
                                                   float* __restrict__ out) {
    __shared__ float w1[64 * 32], w2[32 * 16], w3[16 * 4], bb1[32], bb2[16], bb3[4];
    int tid = threadIdx.x;
    for (int i = tid; i < 2048; i += 256) w1[i] = W1[i];
    for (int i = tid; i < 512; i += 256) w2[i] = W2[i];
    if (tid < 64) w3[tid] = W3[tid];
    if (tid < 32) bb1[tid] = b1[tid];
    if (tid < 16) bb2[tid] = b2[tid];
    if (tid < 4) bb3[tid] = b3[tid];
    __syncthreads();
    int node = blockIdx.x * 256 + tid;
    if (node >= NN) return;

    float a[64];
    #pragma unroll
    for (int k = 0; k < 64; ++k) a[k] = acc[(size_t)node * HH + k];

    float h1[32];
    for (int j = 0; j < 32; ++j) {
        float s = bb1[j];
        #pragma unroll
        for (int k = 0; k < 64; ++k) s += a[k] * w1[k * 32 + j];
        h1[j] = fmaxf(s, 0.f);
    }
    float h2[16];
    for (int j = 0; j < 16; ++j) {
        float s = bb2[j];
        #pragma unroll
        for (int k = 0; k < 32; ++k) s += h1[k] * w2[k * 16 + j];
        h2[j] = fmaxf(s, 0.f);
    }
    float l[4];
    for (int c = 0; c < 4; ++c) {
        float s = bb3[c];
        #pragma unroll
        for (int k = 0; k < 16; ++k) s += h2[k] * w3[k * 4 + c];
        l[c] = s;
    }
    float m = fmaxf(fmaxf(l[0], l[1]), fmaxf(l[2], l[3]));
    float sum = 0.f;
    #pragma unroll
    for (int c = 0; c < 4; ++c) sum += expf(l[c] - m);
    float lse = logf(sum);
    float4 o;
    o.x = l[0] - m - lse; o.y = l[1] - m - lse; o.z = l[2] - m - lse; o.w = l[3] - m - lse;
    *reinterpret_cast<float4*>(&out[(size_t)node * CC]) = o;
}

extern "C" void kernel_launch(void* const* d_in, const int* in_sizes, int n_in,
                              void* d_out, int out_size, void* d_ws, size_t ws_size,
                              hipStream_t stream) {
    const float* x    = (const float*)d_in[0];
    const int*  edges = (const int*)d_in[1];
    const float* Wg   = (const float*)d_in[2];
    const float* bg   = (const float*)d_in[3];
    const float* W1   = (const float*)d_in[4];
    const float* b1   = (const float*)d_in[5];
    const float* W2   = (const float*)d_in[6];
    const float* b2   = (const float*)d_in[7];
    const float* W3   = (const float*)d_in[8];
    const float* b3   = (const float*)d_in[9];
    float* out = (float*)d_out;

    char* ws = (char*)d_ws;
    size_t o = 0;
    int* gcur      = (int*)(ws + o); o += (size_t)TT * NB2 * 4;            // 12.5 KB
    o = (o + 255) & ~(size_t)255;
    int* cnt       = (int*)(ws + o); o += (size_t)TT * NN * 4;             // 1.6 MB
    u32* nodeinfo  = (u32*)(ws + o); o += (size_t)TT * NN * 4;             // 1.6 MB
    o = (o + 255) & ~(size_t)255;
    u16* wt        = (u16*)(ws + o); o += (size_t)TT * HH * FF * 2;        // 128 KB
    o = (o + 255) & ~(size_t)255;
    u32* binned    = (u32*)(ws + o); o += (size_t)TT * NB2 * CAP * 4;      // 32.0 MB
    u16* srclist   = (u16*)(ws + o); o += (size_t)TT * NB2 * CAP * 2;      // 16.0 MB
    u16* y         = (u16*)(ws + o); o += (size_t)TT * NN * HH * 2;        // 51.2 MB
    float* acc     = (float*)(ws + o); o += (size_t)NN * HH * 4;           // 12.8 MB
    // total ~115 MB

    zero_kernel<<<(TT * NN + TT * NB2 + 255) / 256, 256, 0, stream>>>(cnt, gcur);

    wt_prep_kernel<<<TT, 256, 0, stream>>>(Wg, wt);

    multisplit_kernel<<<BPT * TT, 256, 0, stream>>>(edges, gcur, binned, cnt);

    build_kernel<<<XWB * TT + NB2 * TT, 512, 0, stream>>>(binned, gcur, cnt, srclist, nodeinfo,
                                                          x, wt, y);

    agg_kernel<<<12500, 256, 0, stream>>>(y, nodeinfo, srclist, bg, acc);

    head_kernel<<<196, 256, 0, stream>>>(acc, W1, b1, W2, b2, W3, b3, out);
}

// Round 19
// 322.545 us; speedup vs baseline: 1.8097x; 1.8097x over previous
//
#include <hip/hip_runtime.h>
#include <hip/hip_bf16.h>

#define TT 8
#define NN 50000
#define FF 128
#define HH 64
#define CC 4
#define EE 800000
#define NB2 391           // buckets of 128 nodes (ceil(50000/128))
#define CAP 2560          // padded records per (t,bucket): mean 2048, sd ~45 -> 11 sigma
#define BPT 125           // multisplit blocks per timestep (125*6400 = 800000)
#define XWB 391           // xw blocks per timestep (391*128 >= 50000 rows)

typedef unsigned short u16;
typedef unsigned int u32;
typedef __attribute__((ext_vector_type(8))) short bf16x8;
typedef __attribute__((ext_vector_type(4))) float f32x4;
typedef __attribute__((ext_vector_type(4))) int i32x4;

static __device__ __forceinline__ float bflo(u32 w) {
    union { unsigned int i; float f; } v; v.i = w << 16; return v.f;
}
static __device__ __forceinline__ float bfhi(u32 w) {
    union { unsigned int i; float f; } v; v.i = w & 0xFFFF0000u; return v.f;
}
static __device__ __forceinline__ u16 cvt_bf16(float f) {
    __hip_bfloat16 b = __float2bfloat16(f);          // native RNE
    return *reinterpret_cast<u16*>(&b);
}

// ---------------- zero gcur ----------------
__global__ __launch_bounds__(256) void zero_gcur_kernel(int* __restrict__ gcur) {
    int i = blockIdx.x * 256 + threadIdx.x;
    if (i < TT * NB2) gcur[i] = 0;
}

// ---------------- W transpose + bf16 convert (once per t) ----------------
__global__ __launch_bounds__(256) void wt_prep_kernel(const float* __restrict__ Wg, u16* __restrict__ wt) {
    int t = blockIdx.x;
    const float* w = Wg + t * FF * HH;
    u16* o = wt + (size_t)t * HH * FF;
    for (int i = threadIdx.x; i < FF * HH; i += 256) {
        int k = i >> 6, c = i & 63;
        o[c * FF + k] = cvt_bf16(w[i]);
    }
}

// ---------------- FUSED: multisplit || xw-unscaled (truly independent) ----------------
// 256 threads, 1:3 interleaved roles. ms path = r17's exact multisplit (NO global hist --
// r18's scattered cnt atomics caused 230MB write amplification). xw path = r13's 128-row
// MFMA tile writing UNSCALED bf16 y (dinv applied later by csr_scatter, which owns the
// degrees in LDS). LDS arena = max(ms 26.6KB, xw 18.4KB).
__global__ __launch_bounds__(256) void ms_xw_kernel(const int* __restrict__ edges,
                                                    int* __restrict__ gcur, u32* __restrict__ binned,
                                                    const float* __restrict__ x, const u16* __restrict__ wt,
                                                    u16* __restrict__ y) {
    __shared__ __align__(16) char smem[26624];
    int bid = blockIdx.x;
    int tid = threadIdx.x;
    // 1:3 interleave: group of 4 = [ms, xw, xw, xw]; tail blocks are xw
    int isMs, id;
    if (bid < 4 * BPT * TT) {
        isMs = ((bid & 3) == 0);
        id = isMs ? (bid >> 2) : ((bid >> 2) * 3 + (bid & 3) - 1);
    } else {
        isMs = 0; id = 3 * BPT * TT + (bid - 4 * BPT * TT);
    }

    if (isMs) {
        // ---------- multisplit path (r17-identical) ----------
        u32 (*sbuf)[16] = (u32(*)[16])smem;              // 391*16*4 = 25024B
        int* scnt = (int*)(smem + NB2 * 16 * 4);         // 1564B
        int t = id & 7;
        int blk = id >> 3;                    // 0..BPT-1
        const int per = EE / BPT;             // 6400
        int e0 = blk * per;
        int e1 = e0 + per;

        for (int i = tid; i < NB2; i += 256) scnt[i] = 0;
        __syncthreads();

        const int* es = edges + (size_t)(t * 2 + 0) * EE;
        const int* ed = edges + (size_t)(t * 2 + 1) * EE;
        int* gc = gcur + t * NB2;
        u32* bb = binned + (size_t)t * NB2 * CAP;

        for (int base = e0; base < e1; base += 1024) {
            u32 rec[4]; int pb[4];
            int e = base + tid * 4;
            int nv = 0;
            if (e + 3 < e1) nv = 4;
            else if (e < e1) nv = e1 - e;
            if (nv == 4) {
                i32x4 s4 = *reinterpret_cast<const i32x4*>(&es[e]);
                i32x4 d4 = *reinterpret_cast<const i32x4*>(&ed[e]);
                #pragma unroll
                for (int q = 0; q < 4; ++q) {
                    int b = d4[q] >> 7;
                    u32 r = (u32)s4[q] | ((u32)(d4[q] & 127) << 16);
                    int p = atomicAdd(&scnt[b], 1);
                    if (p < 16) { sbuf[b][p] = r; pb[q] = -1; }
                    else { rec[q] = r; pb[q] = b; }
                }
            } else {
                #pragma unroll
                for (int q = 0; q < 4; ++q) {
                    pb[q] = -1;
                    if (q < nv) {
                        int src = es[e + q], dst = ed[e + q];
                        int b = dst >> 7;
                        u32 r = (u32)src | ((u32)(dst & 127) << 16);
                        int p = atomicAdd(&scnt[b], 1);
                        if (p < 16) sbuf[b][p] = r;
                        else { rec[q] = r; pb[q] = b; }
                    }
                }
            }
            __syncthreads();
            for (int fb = tid; fb < NB2; fb += 256) {
                if (scnt[fb] >= 16) {
                    int g = atomicAdd(&gc[fb], 16);
                    uint4* dp = (uint4*)(bb + (size_t)fb * CAP + g);
                    uint4* sp = (uint4*)&sbuf[fb][0];
                    dp[0] = sp[0]; dp[1] = sp[1]; dp[2] = sp[2]; dp[3] = sp[3];
                    scnt[fb] = 0;
                }
            }
            __syncthreads();
            #pragma unroll
            for (int q = 0; q < 4; ++q) {
                if (pb[q] >= 0) {
                    int p = atomicAdd(&scnt[pb[q]], 1);
                    if (p < 16) sbuf[pb[q]][p] = rec[q];
                    else { int g = atomicAdd(&gc[pb[q]], 1); bb[(size_t)pb[q] * CAP + g] = rec[q]; }
                }
            }
            __syncthreads();
        }
        for (int fb = tid; fb < NB2; fb += 256) {
            int c = scnt[fb];
            if (c > 0) {
                int g = atomicAdd(&gc[fb], c);
                for (int k = 0; k < c; ++k) bb[(size_t)fb * CAP + g + k] = sbuf[fb][k];
            }
        }
    } else {
        // ---------- xw path: y = bf16(x @ Wg) UNSCALED (r13 128-row shape) ----------
        u16 (*ylds)[72] = (u16(*)[72])smem;              // 128*72*2 = 18432B
        int t = id / XWB, xb = id % XWB;
        int row0 = xb * 128;
        int w = tid >> 6, lane = tid & 63;
        int l15 = lane & 15, lg = lane >> 4;
        const float* xt = x + (size_t)t * NN * FF;
        const u16* wtt = wt + (size_t)t * HH * FF;

        f32x4 d[2][4] = {{{0,0,0,0},{0,0,0,0},{0,0,0,0},{0,0,0,0}},
                         {{0,0,0,0},{0,0,0,0},{0,0,0,0},{0,0,0,0}}};
        #pragma unroll
        for (int k0 = 0; k0 < 128; k0 += 32) {
            int kb = k0 + lg * 8;
            union { bf16x8 v; __hip_bfloat162 h[4]; } au[2];
            #pragma unroll
            for (int s = 0; s < 2; ++s) {
                int arow = row0 + w * 32 + s * 16 + l15;
                if (arow < NN) {
                    f32x4 f0 = __builtin_nontemporal_load(reinterpret_cast<const f32x4*>(&xt[(size_t)arow * FF + kb]));
                    f32x4 f1 = __builtin_nontemporal_load(reinterpret_cast<const f32x4*>(&xt[(size_t)arow * FF + kb + 4]));
                    au[s].h[0] = __float22bfloat162_rn(make_float2(f0[0], f0[1]));
                    au[s].h[1] = __float22bfloat162_rn(make_float2(f0[2], f0[3]));
                    au[s].h[2] = __float22bfloat162_rn(make_float2(f1[0], f1[1]));
                    au[s].h[3] = __float22bfloat162_rn(make_float2(f1[2], f1[3]));
                } else {
                    au[s].v = (bf16x8){0,0,0,0,0,0,0,0};
                }
            }
            #pragma unroll
            for (int n = 0; n < 4; ++n) {
                bf16x8 bf = *reinterpret_cast<const bf16x8*>(&wtt[(size_t)(n * 16 + l15) * FF + kb]);
                d[0][n] = __builtin_amdgcn_mfma_f32_16x16x32_bf16(au[0].v, bf, d[0][n], 0, 0, 0);
                d[1][n] = __builtin_amdgcn_mfma_f32_16x16x32_bf16(au[1].v, bf, d[1][n], 0, 0, 0);
            }
        }
        #pragma unroll
        for (int s = 0; s < 2; ++s) {
            int rl = w * 32 + s * 16 + lg * 4;
            #pragma unroll
            for (int n = 0; n < 4; ++n) {
                int col = n * 16 + l15;
                #pragma unroll
                for (int i = 0; i < 4; ++i)
                    ylds[rl + i][col] = cvt_bf16(d[s][n][i]);
            }
        }
        __syncthreads();
        u16* yt = y + (size_t)t * NN * HH;
        #pragma unroll
        for (int it = 0; it < 4; ++it) {
            int idx = it * 256 + tid;
            int r = idx >> 3, c8 = (idx & 7) * 8;
            int grow = row0 + r;
            if (grow < NN)
                *reinterpret_cast<uint4*>(&yt[(size_t)grow * HH + c8]) =
                    *reinterpret_cast<const uint4*>(&ylds[r][c8]);
        }
    }
}

// ---------------- per-bucket: LDS degree hist + wave-scan -> CSR scatter + nodeinfo + y-scale ----------------
// 512 threads (r17). Additionally scales its own 128 y-rows by dinv in place (16KB
// coalesced RMW) -- removes xw's dependency on degrees and deletes the dinv buffer.
__global__ __launch_bounds__(512) void csr_scatter_kernel(const u32* __restrict__ binned, const int* __restrict__ gcur,
                                                          u16* __restrict__ srclist, u32* __restrict__ nodeinfo,
                                                          u16* __restrict__ y) {
    __shared__ u32 recs[CAP];
    __shared__ int hist[128];
    __shared__ int cur[128];
    int b = blockIdx.x, t = blockIdx.y, tid = threadIdx.x;
    int node0 = b * 128;
    int tot = gcur[t * NB2 + b];
    const u32* win = binned + ((size_t)t * NB2 + b) * CAP;

    for (int i = tid; i < tot; i += 512) recs[i] = win[i];
    if (tid < 128) hist[tid] = 0;
    __syncthreads();
    for (int i = tid; i < tot; i += 512) atomicAdd(&hist[recs[i] >> 16], 1);
    __syncthreads();
    if (tid < 64) {
        int v0 = hist[2 * tid], v1 = hist[2 * tid + 1];
        int pair = v0 + v1;
        int inc = pair;
        #pragma unroll
        for (int off = 1; off < 64; off <<= 1) {
            int u = __shfl_up(inc, off, 64);
            if (tid >= off) inc += u;
        }
        int exclp = inc - pair;
        cur[2 * tid] = exclp;
        cur[2 * tid + 1] = exclp + v0;
        int node = node0 + 2 * tid;
        if (node < NN)
            nodeinfo[t * NN + node] = (u32)(b * CAP + exclp) | ((u32)v0 << 20);
        if (node + 1 < NN)
            nodeinfo[t * NN + node + 1] = (u32)(b * CAP + exclp + v0) | ((u32)v1 << 20);
    }
    __syncthreads();
    u16* sl = srclist + (size_t)t * NB2 * CAP;
    for (int i = tid; i < tot; i += 512) {
        u32 rec = recs[i];
        int d = rec >> 16;
        int p = atomicAdd(&cur[d], 1);
        sl[(size_t)b * CAP + p] = (u16)(rec & 0xFFFF);
    }
    // scale this bucket's y rows in place: y[t][node] *= rsqrt(1+deg) (hist preserved)
    u16* yt = y + (size_t)t * NN * HH;
    for (int idx = tid; idx < 128 * 8; idx += 512) {    // 1024 uint4 = 128 rows x 128B
        int r = idx >> 3, c8 = (idx & 7) * 8;
        int grow = node0 + r;
        if (grow < NN) {
            float dv = rsqrtf(1.f + (float)hist[r]);
            uint4* p = reinterpret_cast<uint4*>(&yt[(size_t)grow * HH + c8]);
            uint4 v = *p;
            u32 ww[4] = {v.x, v.y, v.z, v.w};
            #pragma unroll
            for (int k = 0; k < 4; ++k) {
                float lo = bflo(ww[k]) * dv;
                float hi = bfhi(ww[k]) * dv;
                ww[k] = (u32)cvt_bf16(lo) | ((u32)cvt_bf16(hi) << 16);
            }
            *p = make_uint4(ww[0], ww[1], ww[2], ww[3]);
        }
    }
}

// ---------------- gather-aggregate over all T (single pass, full 128B rows) ----------------
// EXACT r8/r17 structure (pinned at 401MB compulsory floor, ~2.5TB/s). dinv from packed degree.
__global__ __launch_bounds__(256) void agg_kernel(const u16* __restrict__ y,
                                                  const u32* __restrict__ nodeinfo, const u16* __restrict__ srclist,
                                                  const float* __restrict__ bg, float* __restrict__ acc) {
    int node = blockIdx.x * 4 + (threadIdx.x >> 6);
    int lane = threadIdx.x & 63;
    int sub = lane >> 4;            // edge slot 0..3
    int fo = lane & 15;             // feature quad: feats fo*4 .. fo*4+3
    float a0 = 0.f, a1 = 0.f, a2 = 0.f, a3 = 0.f;
    for (int t = 0; t < TT; ++t) {
        const u16* yt = y + (size_t)t * NN * HH;
        u32 info = nodeinfo[t * NN + node];
        int cnt = info >> 20;
        const u16* sl = srclist + (size_t)t * NB2 * CAP + (info & 0xFFFFF);
        float s0 = 0.f, s1 = 0.f, s2 = 0.f, s3 = 0.f;
        int j = 0;
        for (; j + 16 <= cnt; j += 16) {
            int e0 = sl[j + sub], e1 = sl[j + 4 + sub], e2 = sl[j + 8 + sub], e3 = sl[j + 12 + sub];
            uint2 v0 = *reinterpret_cast<const uint2*>(&yt[(size_t)e0 * HH + fo * 4]);
            uint2 v1 = *reinterpret_cast<const uint2*>(&yt[(size_t)e1 * HH + fo * 4]);
            uint2 v2 = *reinterpret_cast<const uint2*>(&yt[(size_t)e2 * HH + fo * 4]);
            uint2 v3 = *reinterpret_cast<const uint2*>(&yt[(size_t)e3 * HH + fo * 4]);
            s0 += (bflo(v0.x) + bflo(v1.x)) + (bflo(v2.x) + bflo(v3.x));
            s1 += (bfhi(v0.x) + bfhi(v1.x)) + (bfhi(v2.x) + bfhi(v3.x));
            s2 += (bflo(v0.y) + bflo(v1.y)) + (bflo(v2.y) + bflo(v3.y));
            s3 += (bfhi(v0.y) + bfhi(v1.y)) + (bfhi(v2.y) + bfhi(v3.y));
        }
        for (; j < cnt; j += 4) {
            int e = j + sub;
            uint2 v = make_uint2(0u, 0u);
            if (e < cnt) {
                int srcid = sl[e];
                v = *reinterpret_cast<const uint2*>(&yt[(size_t)srcid * HH + fo * 4]);
            }
            s0 += bflo(v.x);
            s1 += bfhi(v.x);
            s2 += bflo(v.y);
            s3 += bfhi(v.y);
        }
        s0 += __shfl_xor(s0, 16, 64); s0 += __shfl_xor(s0, 32, 64);
        s1 += __shfl_xor(s1, 16, 64); s1 += __shfl_xor(s1, 32, 64);
        s2 += __shfl_xor(s2, 16, 64); s2 += __shfl_xor(s2, 32, 64);
        s3 += __shfl_xor(s3, 16, 64); s3 += __shfl_xor(s3, 32, 64);
        // self loop (y already scaled)
        uint2 sv = *reinterpret_cast<const uint2*>(&yt[(size_t)node * HH + fo * 4]);
        s0 += bflo(sv.x);
        s1 += bfhi(sv.x);
        s2 += bflo(sv.y);
        s3 += bfhi(sv.y);
        float dvv = rsqrtf(1.f + (float)cnt);
        float4 bgv = *reinterpret_cast<const float4*>(&bg[t * HH + fo * 4]);
        a0 += fmaxf(dvv * s0 + bgv.x, 0.f);
        a1 += fmaxf(dvv * s1 + bgv.y, 0.f);
        a2 += fmaxf(dvv * s2 + bgv.z, 0.f);
        a3 += fmaxf(dvv * s3 + bgv.w, 0.f);
    }
    if (sub == 0) {
        float4 o = make_float4(a0, a1, a2, a3);
        *reinterpret_cast<float4*>(&acc[(size_t)node * HH + fo * 4]) = o;
    }
}

// ---------------- per-node MLP head + log_softmax ----------------
__global__ __launch_bounds__(256) void head_kernel(const float* __restrict__ acc,
                                                   const float* __restrict__ W1, const float* __restrict__ b1,
                                                   const float* __restrict__ W2, const float* __restrict__ b2,
                                                   const float* __restrict__ W3, const float* __restrict__ b3,
                                                   float* __restrict__ out) {
    __shared__ float w1[64 * 32], w2[32 * 16], w3[16 * 4], bb1[32], bb2[16], bb3[4];
    int tid = threadIdx.x;
    for (int i = tid; i < 2048; i += 256) w1[i] = W1[i];
    for (int i = tid; i < 512; i += 256) w2[i] = W2[i];
    if (tid < 64) w3[tid] = W3[tid];
    if (tid < 32) bb1[tid] = b1[tid];
    if (tid < 16) bb2[tid] = b2[tid];
    if (tid < 4) bb3[tid] = b3[tid];
    __syncthreads();
    int node = blockIdx.x * 256 + tid;
    if (node >= NN) return;

    float a[64];
    #pragma unroll
    for (int k = 0; k < 64; ++k) a[k] = acc[(size_t)node * HH + k];

    float h1[32];
    for (int j = 0; j < 32; ++j) {
        float s = bb1[j];
        #pragma unroll
        for (int k = 0; k < 64; ++k) s += a[k] * w1[k * 32 + j];
        h1[j] = fmaxf(s, 0.f);
    }
    float h2[16];
    for (int j = 0; j < 16; ++j) {
        float s = bb2[j];
        #pragma unroll
        for (int k = 0; k < 32; ++k) s += h1[k] * w2[k * 16 + j];
        h2[j] = fmaxf(s, 0.f);
    }
    float l[4];
    for (int c = 0; c < 4; ++c) {
        float s = bb3[c];
        #pragma unroll
        for (int k = 0; k < 16; ++k) s += h2[k] * w3[k * 4 + c];
        l[c] = s;
    }
    float m = fmaxf(fmaxf(l[0], l[1]), fmaxf(l[2], l[3]));
    float sum = 0.f;
    #pragma unroll
    for (int c = 0; c < 4; ++c) sum += expf(l[c] - m);
    float lse = logf(sum);
    float4 o;
    o.x = l[0] - m - lse; o.y = l[1] - m - lse; o.z = l[2] - m - lse; o.w = l[3] - m - lse;
    *reinterpret_cast<float4*>(&out[(size_t)node * CC]) = o;
}

extern "C" void kernel_launch(void* const* d_in, const int* in_sizes, int n_in,
                              void* d_out, int out_size, void* d_ws, size_t ws_size,
                              hipStream_t stream) {
    const float* x    = (const float*)d_in[0];
    const int*  edges = (const int*)d_in[1];
    const float* Wg   = (const float*)d_in[2];
    const float* bg   = (const float*)d_in[3];
    const float* W1   = (const float*)d_in[4];
    const float* b1   = (const float*)d_in[5];
    const float* W2   = (const float*)d_in[6];
    const float* b2   = (const float*)d_in[7];
    const float* W3   = (const float*)d_in[8];
    const float* b3   = (const float*)d_in[9];
    float* out = (float*)d_out;

    char* ws = (char*)d_ws;
    size_t o = 0;
    int* gcur      = (int*)(ws + o); o += (size_t)TT * NB2 * 4;            // 12.5 KB
    o = (o + 255) & ~(size_t)255;
    u32* nodeinfo  = (u32*)(ws + o); o += (size_t)TT * NN * 4;             // 1.6 MB
    o = (o + 255) & ~(size_t)255;
    u16* wt        = (u16*)(ws + o); o += (size_t)TT * HH * FF * 2;        // 128 KB
    o = (o + 255) & ~(size_t)255;
    u32* binned    = (u32*)(ws + o); o += (size_t)TT * NB2 * CAP * 4;      // 32.0 MB
    u16* srclist   = (u16*)(ws + o); o += (size_t)TT * NB2 * CAP * 2;      // 16.0 MB
    u16* y         = (u16*)(ws + o); o += (size_t)TT * NN * HH * 2;        // 51.2 MB
    float* acc     = (float*)(ws + o); o += (size_t)NN * HH * 4;           // 12.8 MB
    // total ~114 MB

    zero_gcur_kernel<<<(TT * NB2 + 255) / 256, 256, 0, stream>>>(gcur);

    wt_prep_kernel<<<TT, 256, 0, stream>>>(Wg, wt);

    // fused multisplit || xw-unscaled: 1000 ms blocks + 3128 xw blocks, 1:3 interleave
    ms_xw_kernel<<<4 * BPT * TT + (XWB * TT - 3 * BPT * TT), 256, 0, stream>>>(
        edges, gcur, binned, x, wt, y);

    dim3 gsc(NB2, TT);
    csr_scatter_kernel<<<gsc, 512, 0, stream>>>(binned, gcur, srclist, nodeinfo, y);

    agg_kernel<<<12500, 256, 0, stream>>>(y, nodeinfo, srclist, bg, acc);

    head_kernel<<<196, 256, 0, stream>>>(acc, W1, b1, W2, b2, W3, b3, out);
}

// Round 20
// 321.508 us; speedup vs baseline: 1.8155x; 1.0032x over previous
//
#include <hip/hip_runtime.h>
#include <hip/hip_bf16.h>

#define TT 8
#define NN 50000
#define FF 128
#define HH 64
#define CC 4
#define EE 800000
#define NB2 391           // buckets of 128 nodes (ceil(50000/128))
#define CAP 2560          // padded records per (t,bucket): mean 2048, sd ~45 -> 11 sigma
#define BPT 125           // multisplit blocks per timestep (125*6400 = 800000)
#define XWB 391           // xw blocks per timestep (391*128 >= 50000 rows)

typedef unsigned short u16;
typedef unsigned int u32;
typedef __attribute__((ext_vector_type(8))) short bf16x8;
typedef __attribute__((ext_vector_type(4))) float f32x4;
typedef __attribute__((ext_vector_type(4))) int i32x4;

static __device__ __forceinline__ float bflo(u32 w) {
    union { unsigned int i; float f; } v; v.i = w << 16; return v.f;
}
static __device__ __forceinline__ float bfhi(u32 w) {
    union { unsigned int i; float f; } v; v.i = w & 0xFFFF0000u; return v.f;
}
static __device__ __forceinline__ float bf2f(u16 u) {
    union { unsigned int i; float f; } v; v.i = ((unsigned int)u) << 16; return v.f;
}
static __device__ __forceinline__ u16 cvt_bf16(float f) {
    __hip_bfloat16 b = __float2bfloat16(f);          // native RNE
    return *reinterpret_cast<u16*>(&b);
}

// ---------------- zero gcur ----------------
__global__ __launch_bounds__(256) void zero_gcur_kernel(int* __restrict__ gcur) {
    int i = blockIdx.x * 256 + threadIdx.x;
    if (i < TT * NB2) gcur[i] = 0;
}

// ---------------- W transpose + bf16 convert (once per t) ----------------
__global__ __launch_bounds__(256) void wt_prep_kernel(const float* __restrict__ Wg, u16* __restrict__ wt) {
    int t = blockIdx.x;
    const float* w = Wg + t * FF * HH;
    u16* o = wt + (size_t)t * HH * FF;
    for (int i = threadIdx.x; i < FF * HH; i += 256) {
        int k = i >> 6, c = i & 63;
        o[c * FF + k] = cvt_bf16(w[i]);
    }
}

// ---------------- FUSED: multisplit || xw-unscaled (truly independent) ----------------
// 256 threads, 1:3 interleaved roles. ms path = r17's exact multisplit. xw path = r13's
// 128-row MFMA tile writing UNSCALED bf16 y (dinv applied in agg via dv16 FMA).
__global__ __launch_bounds__(256) void ms_xw_kernel(const int* __restrict__ edges,
                                                    int* __restrict__ gcur, u32* __restrict__ binned,
                                                    const float* __restrict__ x, const u16* __restrict__ wt,
                                                    u16* __restrict__ y) {
    __shared__ __align__(16) char smem[26624];
    int bid = blockIdx.x;
    int tid = threadIdx.x;
    // 1:3 interleave: group of 4 = [ms, xw, xw, xw]; tail blocks are xw
    int isMs, id;
    if (bid < 4 * BPT * TT) {
        isMs = ((bid & 3) == 0);
        id = isMs ? (bid >> 2) : ((bid >> 2) * 3 + (bid & 3) - 1);
    } else {
        isMs = 0; id = 3 * BPT * TT + (bid - 4 * BPT * TT);
    }

    if (isMs) {
        // ---------- multisplit path ----------
        u32 (*sbuf)[16] = (u32(*)[16])smem;              // 391*16*4 = 25024B
        int* scnt = (int*)(smem + NB2 * 16 * 4);         // 1564B
        int t = id & 7;
        int blk = id >> 3;                    // 0..BPT-1
        const int per = EE / BPT;             // 6400
        int e0 = blk * per;
        int e1 = e0 + per;

        for (int i = tid; i < NB2; i += 256) scnt[i] = 0;
        __syncthreads();

        const int* es = edges + (size_t)(t * 2 + 0) * EE;
        const int* ed = edges + (size_t)(t * 2 + 1) * EE;
        int* gc = gcur + t * NB2;
        u32* bb = binned + (size_t)t * NB2 * CAP;

        for (int base = e0; base < e1; base += 1024) {
            u32 rec[4]; int pb[4];
            int e = base + tid * 4;
            int nv = 0;
            if (e + 3 < e1) nv = 4;
            else if (e < e1) nv = e1 - e;
            if (nv == 4) {
                i32x4 s4 = *reinterpret_cast<const i32x4*>(&es[e]);
                i32x4 d4 = *reinterpret_cast<const i32x4*>(&ed[e]);
                #pragma unroll
                for (int q = 0; q < 4; ++q) {
                    int b = d4[q] >> 7;
                    u32 r = (u32)s4[q] | ((u32)(d4[q] & 127) << 16);
                    int p = atomicAdd(&scnt[b], 1);
                    if (p < 16) { sbuf[b][p] = r; pb[q] = -1; }
                    else { rec[q] = r; pb[q] = b; }
                }
            } else {
                #pragma unroll
                for (int q = 0; q < 4; ++q) {
                    pb[q] = -1;
                    if (q < nv) {
                        int src = es[e + q], dst = ed[e + q];
                        int b = dst >> 7;
                        u32 r = (u32)src | ((u32)(dst & 127) << 16);
                        int p = atomicAdd(&scnt[b], 1);
                        if (p < 16) sbuf[b][p] = r;
                        else { rec[q] = r; pb[q] = b; }
                    }
                }
            }
            __syncthreads();
            for (int fb = tid; fb < NB2; fb += 256) {
                if (scnt[fb] >= 16) {
                    int g = atomicAdd(&gc[fb], 16);
                    uint4* dp = (uint4*)(bb + (size_t)fb * CAP + g);
                    uint4* sp = (uint4*)&sbuf[fb][0];
                    dp[0] = sp[0]; dp[1] = sp[1]; dp[2] = sp[2]; dp[3] = sp[3];
                    scnt[fb] = 0;
                }
            }
            __syncthreads();
            #pragma unroll
            for (int q = 0; q < 4; ++q) {
                if (pb[q] >= 0) {
                    int p = atomicAdd(&scnt[pb[q]], 1);
                    if (p < 16) sbuf[pb[q]][p] = rec[q];
                    else { int g = atomicAdd(&gc[pb[q]], 1); bb[(size_t)pb[q] * CAP + g] = rec[q]; }
                }
            }
            __syncthreads();
        }
        for (int fb = tid; fb < NB2; fb += 256) {
            int c = scnt[fb];
            if (c > 0) {
                int g = atomicAdd(&gc[fb], c);
                for (int k = 0; k < c; ++k) bb[(size_t)fb * CAP + g + k] = sbuf[fb][k];
            }
        }
    } else {
        // ---------- xw path: y = bf16(x @ Wg) UNSCALED ----------
        u16 (*ylds)[72] = (u16(*)[72])smem;              // 128*72*2 = 18432B
        int t = id / XWB, xb = id % XWB;
        int row0 = xb * 128;
        int w = tid >> 6, lane = tid & 63;
        int l15 = lane & 15, lg = lane >> 4;
        const float* xt = x + (size_t)t * NN * FF;
        const u16* wtt = wt + (size_t)t * HH * FF;

        f32x4 d[2][4] = {{{0,0,0,0},{0,0,0,0},{0,0,0,0},{0,0,0,0}},
                         {{0,0,0,0},{0,0,0,0},{0,0,0,0},{0,0,0,0}}};
        #pragma unroll
        for (int k0 = 0; k0 < 128; k0 += 32) {
            int kb = k0 + lg * 8;
            union { bf16x8 v; __hip_bfloat162 h[4]; } au[2];
            #pragma unroll
            for (int s = 0; s < 2; ++s) {
                int arow = row0 + w * 32 + s * 16 + l15;
                if (arow < NN) {
                    f32x4 f0 = __builtin_nontemporal_load(reinterpret_cast<const f32x4*>(&xt[(size_t)arow * FF + kb]));
                    f32x4 f1 = __builtin_nontemporal_load(reinterpret_cast<const f32x4*>(&xt[(size_t)arow * FF + kb + 4]));
                    au[s].h[0] = __float22bfloat162_rn(make_float2(f0[0], f0[1]));
                    au[s].h[1] = __float22bfloat162_rn(make_float2(f0[2], f0[3]));
                    au[s].h[2] = __float22bfloat162_rn(make_float2(f1[0], f1[1]));
                    au[s].h[3] = __float22bfloat162_rn(make_float2(f1[2], f1[3]));
                } else {
                    au[s].v = (bf16x8){0,0,0,0,0,0,0,0};
                }
            }
            #pragma unroll
            for (int n = 0; n < 4; ++n) {
                bf16x8 bf = *reinterpret_cast<const bf16x8*>(&wtt[(size_t)(n * 16 + l15) * FF + kb]);
                d[0][n] = __builtin_amdgcn_mfma_f32_16x16x32_bf16(au[0].v, bf, d[0][n], 0, 0, 0);
                d[1][n] = __builtin_amdgcn_mfma_f32_16x16x32_bf16(au[1].v, bf, d[1][n], 0, 0, 0);
            }
        }
        #pragma unroll
        for (int s = 0; s < 2; ++s) {
            int rl = w * 32 + s * 16 + lg * 4;
            #pragma unroll
            for (int n = 0; n < 4; ++n) {
                int col = n * 16 + l15;
                #pragma unroll
                for (int i = 0; i < 4; ++i)
                    ylds[rl + i][col] = cvt_bf16(d[s][n][i]);
            }
        }
        __syncthreads();
        u16* yt = y + (size_t)t * NN * HH;
        #pragma unroll
        for (int it = 0; it < 4; ++it) {
            int idx = it * 256 + tid;
            int r = idx >> 3, c8 = (idx & 7) * 8;
            int grow = row0 + r;
            if (grow < NN)
                *reinterpret_cast<uint4*>(&yt[(size_t)grow * HH + c8]) =
                    *reinterpret_cast<const uint4*>(&ylds[r][c8]);
        }
    }
}

// ---------------- per-bucket: LDS degree hist + wave-scan -> CSR scatter + nodeinfo + dv16 ----------------
// No y-RMW anymore: agg applies dinv[src] itself via the bf16 dv16 table written here.
__global__ __launch_bounds__(512) void csr_scatter_kernel(const u32* __restrict__ binned, const int* __restrict__ gcur,
                                                          u16* __restrict__ srclist, u32* __restrict__ nodeinfo,
                                                          u16* __restrict__ dv16) {
    __shared__ u32 recs[CAP];
    __shared__ int hist[128];
    __shared__ int cur[128];
    int b = blockIdx.x, t = blockIdx.y, tid = threadIdx.x;
    int node0 = b * 128;
    int tot = gcur[t * NB2 + b];
    const u32* win = binned + ((size_t)t * NB2 + b) * CAP;

    for (int i = tid; i < tot; i += 512) recs[i] = win[i];
    if (tid < 128) hist[tid] = 0;
    __syncthreads();
    for (int i = tid; i < tot; i += 512) atomicAdd(&hist[recs[i] >> 16], 1);
    __syncthreads();
    if (tid < 64) {
        int v0 = hist[2 * tid], v1 = hist[2 * tid + 1];
        int pair = v0 + v1;
        int inc = pair;
        #pragma unroll
        for (int off = 1; off < 64; off <<= 1) {
            int u = __shfl_up(inc, off, 64);
            if (tid >= off) inc += u;
        }
        int exclp = inc - pair;
        cur[2 * tid] = exclp;
        cur[2 * tid + 1] = exclp + v0;
        int node = node0 + 2 * tid;
        if (node < NN)
            nodeinfo[t * NN + node] = (u32)(b * CAP + exclp) | ((u32)v0 << 20);
        if (node + 1 < NN)
            nodeinfo[t * NN + node + 1] = (u32)(b * CAP + exclp + v0) | ((u32)v1 << 20);
    }
    // dv16 = bf16(rsqrt(1+deg)) for this bucket's nodes (hist intact: scan wrote cur only)
    if (tid < 128) {
        int node = node0 + tid;
        if (node < NN) dv16[t * NN + node] = cvt_bf16(rsqrtf(1.f + (float)hist[tid]));
    }
    __syncthreads();
    u16* sl = srclist + (size_t)t * NB2 * CAP;
    for (int i = tid; i < tot; i += 512) {
        u32 rec = recs[i];
        int d = rec >> 16;
        int p = atomicAdd(&cur[d], 1);
        sl[(size_t)b * CAP + p] = (u16)(rec & 0xFFFF);
    }
}

// ---------------- gather-aggregate over all T (single pass, full 128B rows) ----------------
// r8 structure; y is UNSCALED: dinv[src] applied via dv16 gather (2B, L2-resident 100KB/t)
// + FMA (same VALU rate as the old add).
__global__ __launch_bounds__(256) void agg_kernel(const u16* __restrict__ y,
                                                  const u32* __restrict__ nodeinfo, const u16* __restrict__ srclist,
                                                  const u16* __restrict__ dv16,
                                                  const float* __restrict__ bg, float* __restrict__ acc) {
    int node = blockIdx.x * 4 + (threadIdx.x >> 6);
    int lane = threadIdx.x & 63;
    int sub = lane >> 4;            // edge slot 0..3
    int fo = lane & 15;             // feature quad: feats fo*4 .. fo*4+3
    float a0 = 0.f, a1 = 0.f, a2 = 0.f, a3 = 0.f;
    for (int t = 0; t < TT; ++t) {
        const u16* yt = y + (size_t)t * NN * HH;
        const u16* dvt = dv16 + (size_t)t * NN;
        u32 info = nodeinfo[t * NN + node];
        int cnt = info >> 20;
        const u16* sl = srclist + (size_t)t * NB2 * CAP + (info & 0xFFFFF);
        float s0 = 0.f, s1 = 0.f, s2 = 0.f, s3 = 0.f;
        int j = 0;
        for (; j + 16 <= cnt; j += 16) {
            int e0 = sl[j + sub], e1 = sl[j + 4 + sub], e2 = sl[j + 8 + sub], e3 = sl[j + 12 + sub];
            float d0 = bf2f(dvt[e0]), d1 = bf2f(dvt[e1]), d2 = bf2f(dvt[e2]), d3 = bf2f(dvt[e3]);
            uint2 v0 = *reinterpret_cast<const uint2*>(&yt[(size_t)e0 * HH + fo * 4]);
            uint2 v1 = *reinterpret_cast<const uint2*>(&yt[(size_t)e1 * HH + fo * 4]);
            uint2 v2 = *reinterpret_cast<const uint2*>(&yt[(size_t)e2 * HH + fo * 4]);
            uint2 v3 = *reinterpret_cast<const uint2*>(&yt[(size_t)e3 * HH + fo * 4]);
            s0 += bflo(v0.x) * d0 + bflo(v1.x) * d1 + bflo(v2.x) * d2 + bflo(v3.x) * d3;
            s1 += bfhi(v0.x) * d0 + bfhi(v1.x) * d1 + bfhi(v2.x) * d2 + bfhi(v3.x) * d3;
            s2 += bflo(v0.y) * d0 + bflo(v1.y) * d1 + bflo(v2.y) * d2 + bflo(v3.y) * d3;
            s3 += bfhi(v0.y) * d0 + bfhi(v1.y) * d1 + bfhi(v2.y) * d2 + bfhi(v3.y) * d3;
        }
        for (; j < cnt; j += 4) {
            int e = j + sub;
            if (e < cnt) {
                int srcid = sl[e];
                float dd = bf2f(dvt[srcid]);
                uint2 v = *reinterpret_cast<const uint2*>(&yt[(size_t)srcid * HH + fo * 4]);
                s0 += bflo(v.x) * dd;
                s1 += bfhi(v.x) * dd;
                s2 += bflo(v.y) * dd;
                s3 += bfhi(v.y) * dd;
            }
        }
        s0 += __shfl_xor(s0, 16, 64); s0 += __shfl_xor(s0, 32, 64);
        s1 += __shfl_xor(s1, 16, 64); s1 += __shfl_xor(s1, 32, 64);
        s2 += __shfl_xor(s2, 16, 64); s2 += __shfl_xor(s2, 32, 64);
        s3 += __shfl_xor(s3, 16, 64); s3 += __shfl_xor(s3, 32, 64);
        // self loop: y unscaled -> scale by own dinv
        float dvv = bf2f(dvt[node]);
        uint2 sv = *reinterpret_cast<const uint2*>(&yt[(size_t)node * HH + fo * 4]);
        s0 += bflo(sv.x) * dvv;
        s1 += bfhi(sv.x) * dvv;
        s2 += bflo(sv.y) * dvv;
        s3 += bfhi(sv.y) * dvv;
        float4 bgv = *reinterpret_cast<const float4*>(&bg[t * HH + fo * 4]);
        a0 += fmaxf(dvv * s0 + bgv.x, 0.f);
        a1 += fmaxf(dvv * s1 + bgv.y, 0.f);
        a2 += fmaxf(dvv * s2 + bgv.z, 0.f);
        a3 += fmaxf(dvv * s3 + bgv.w, 0.f);
    }
    if (sub == 0) {
        float4 o = make_float4(a0, a1, a2, a3);
        *reinterpret_cast<float4*>(&acc[(size_t)node * HH + fo * 4]) = o;
    }
}

// ---------------- per-node MLP head + log_softmax ----------------
__global__ __launch_bounds__(256) void head_kernel(const float* __restrict__ acc,
                                                   const float* __restrict__ W1, const float* __restrict__ b1,
                                                   const float* __restrict__ W2, const float* __restrict__ b2,
                                                   const float* __restrict__ W3, const float* __restrict__ b3,
                                                   float* __restrict__ out) {
    __shared__ float w1[64 * 32], w2[32 * 16], w3[16 * 4], bb1[32], bb2[16], bb3[4];
    int tid = threadIdx.x;
    for (int i = tid; i < 2048; i += 256) w1[i] = W1[i];
    for (int i = tid; i < 512; i += 256) w2[i] = W2[i];
    if (tid < 64) w3[tid] = W3[tid];
    if (tid < 32) bb1[tid] = b1[tid];
    if (tid < 16) bb2[tid] = b2[tid];
    if (tid < 4) bb3[tid] = b3[tid];
    __syncthreads();
    int node = blockIdx.x * 256 + tid;
    if (node >= NN) return;

    float a[64];
    #pragma unroll
    for (int k = 0; k < 64; ++k) a[k] = acc[(size_t)node * HH + k];

    float h1[32];
    for (int j = 0; j < 32; ++j) {
        float s = bb1[j];
        #pragma unroll
        for (int k = 0; k < 64; ++k) s += a[k] * w1[k * 32 + j];
        h1[j] = fmaxf(s, 0.f);
    }
    float h2[16];
    for (int j = 0; j < 16; ++j) {
        float s = bb2[j];
        #pragma unroll
        for (int k = 0; k < 32; ++k) s += h1[k] * w2[k * 16 + j];
        h2[j] = fmaxf(s, 0.f);
    }
    float l[4];
    for (int c = 0; c < 4; ++c) {
        float s = bb3[c];
        #pragma unroll
        for (int k = 0; k < 16; ++k) s += h2[k] * w3[k * 4 + c];
        l[c] = s;
    }
    float m = fmaxf(fmaxf(l[0], l[1]), fmaxf(l[2], l[3]));
    float sum = 0.f;
    #pragma unroll
    for (int c = 0; c < 4; ++c) sum += expf(l[c] - m);
    float lse = logf(sum);
    float4 o;
    o.x = l[0] - m - lse; o.y = l[1] - m - lse; o.z = l[2] - m - lse; o.w = l[3] - m - lse;
    *reinterpret_cast<float4*>(&out[(size_t)node * CC]) = o;
}

extern "C" void kernel_launch(void* const* d_in, const int* in_sizes, int n_in,
                              void* d_out, int out_size, void* d_ws, size_t ws_size,
                              hipStream_t stream) {
    const float* x    = (const float*)d_in[0];
    const int*  edges = (const int*)d_in[1];
    const float* Wg   = (const float*)d_in[2];
    const float* bg   = (const float*)d_in[3];
    const float* W1   = (const float*)d_in[4];
    const float* b1   = (const float*)d_in[5];
    const float* W2   = (const float*)d_in[6];
    const float* b2   = (const float*)d_in[7];
    const float* W3   = (const float*)d_in[8];
    const float* b3   = (const float*)d_in[9];
    float* out = (float*)d_out;

    char* ws = (char*)d_ws;
    size_t o = 0;
    int* gcur      = (int*)(ws + o); o += (size_t)TT * NB2 * 4;            // 12.5 KB
    o = (o + 255) & ~(size_t)255;
    u32* nodeinfo  = (u32*)(ws + o); o += (size_t)TT * NN * 4;             // 1.6 MB
    u16* dv16      = (u16*)(ws + o); o += (size_t)TT * NN * 2;             // 0.8 MB
    o = (o + 255) & ~(size_t)255;
    u16* wt        = (u16*)(ws + o); o += (size_t)TT * HH * FF * 2;        // 128 KB
    o = (o + 255) & ~(size_t)255;
    u32* binned    = (u32*)(ws + o); o += (size_t)TT * NB2 * CAP * 4;      // 32.0 MB
    u16* srclist   = (u16*)(ws + o); o += (size_t)TT * NB2 * CAP * 2;      // 16.0 MB
    u16* y         = (u16*)(ws + o); o += (size_t)TT * NN * HH * 2;        // 51.2 MB
    float* acc     = (float*)(ws + o); o += (size_t)NN * HH * 4;           // 12.8 MB
    // total ~115 MB

    zero_gcur_kernel<<<(TT * NB2 + 255) / 256, 256, 0, stream>>>(gcur);

    wt_prep_kernel<<<TT, 256, 0, stream>>>(Wg, wt);

    // fused multisplit || xw-unscaled: 1000 ms blocks + 3128 xw blocks, 1:3 interleave
    ms_xw_kernel<<<4 * BPT * TT + (XWB * TT - 3 * BPT * TT), 256, 0, stream>>>(
        edges, gcur, binned, x, wt, y);

    dim3 gsc(NB2, TT);
    csr_scatter_kernel<<<gsc, 512, 0, stream>>>(binned, gcur, srclist, nodeinfo, dv16);

    agg_kernel<<<12500, 256, 0, stream>>>(y, nodeinfo, srclist, dv16, bg, acc);

    head_kernel<<<196, 256, 0, stream>>>(acc, W1, b1, W2, b2, W3, b3, out);
}